// Round 5
// baseline (674.718 us; speedup 1.0000x reference)
//
#include <hip/hip_runtime.h>

#define DEVFN __device__ __forceinline__

constexpr int N    = 100000;
constexpr int F_IN = 166;
constexpr int HID  = 128;
constexpr int E    = 1600000;
constexpr int TOT  = E + N;          // edges + self-loops

// ---- workspace layout (bytes, all 16B-aligned) ----
constexpr size_t HW_OFF   = 0;            // hW [N,128] f32      51.2 MB
constexpr size_t ASRC_OFF = 51200000;     // a_src [N,4] f32      1.6 MB
constexpr size_t ADST_OFF = 52800000;     // a_dst [N,4] f32      1.6 MB
constexpr size_t DEG_OFF  = 54400000;     // deg [N] i32        400 KB (zeroed)
constexpr size_t ROW_OFF  = 54800000;     // rowstart [N+1] i32
constexpr size_t CUR_OFF  = 55300000;     // cursor [N] i32
constexpr size_t BSUM_OFF = 55700000;     // block sums [128] i32
constexpr size_t CSR_OFF  = 55710000;     // csr_src [TOT] i32   27.2 MB
constexpr size_t GOUT_OFF = 82910016;     // gat out [N,128] f32 51.2 MB

constexpr int SCAN_ELEMS = 1024;
constexpr int SCAN_NB    = (N + SCAN_ELEMS - 1) / SCAN_ELEMS;  // 98

DEVFN float lrelu(float e) { return e > 0.0f ? e : 0.2f * e; }

// ---------------------------------------------------------------------------
// K1: h = relu(x@W_in+b_in), hW = h@W_gat, a_src/a_dst = per-head hW·att
// Tile 32 rows x 128 cols, 256 threads, 4 rows x 4 cols per thread.
// W staged in LDS in 32-k-row chunks (16 KB), cooperatively loaded once per
// BLOCK (vs once per wave from global in R4 -> 4x less L1/L2 W traffic and
// no per-wave 200-cyc L2 dependency in the k-loop).
// xs zero-padded to K=168; hs reuses the xs buffer (stride 132).
// ---------------------------------------------------------------------------
__global__ __launch_bounds__(256) void k_proj(
    const float* __restrict__ x, const float* __restrict__ Win,
    const float* __restrict__ bin, const float* __restrict__ Wgat,
    const float* __restrict__ attS, const float* __restrict__ attD,
    float* __restrict__ hW, float* __restrict__ aS, float* __restrict__ aD)
{
    __shared__ __align__(16) float xs[32 * 168];   // x tile; later hs (stride 132)
    __shared__ __align__(16) float Ws[32 * 128];   // W chunk

    float* hs = xs;

    const int t = threadIdx.x;
    const int row0 = blockIdx.x * 32;
    const int cgrp = t & 31, rgrp = t >> 5;
    const int c0 = cgrp * 4;          // 4 cols
    const int r0 = rgrp * 4;          // 4 rows

    // ---- stage x tile (row-major, stride 168), float2 granules ----
    for (int idx = t; idx < 32 * 83; idx += 256) {
        const int r = idx / 83, kk = idx - r * 83;
        const float2 v = *(const float2*)&x[(size_t)(row0 + r) * F_IN + 2 * kk];
        *(float2*)&xs[r * 168 + 2 * kk] = v;
    }
    if (t < 32) { xs[t * 168 + 166] = 0.0f; xs[t * 168 + 167] = 0.0f; }
    // (no sync needed yet; first chunk's post-load barrier covers xs too)

    // ---- GEMM1: h = relu(x@Win + bin), K padded to 168 ----
    float acc[4][4];
#pragma unroll
    for (int r = 0; r < 4; ++r)
#pragma unroll
        for (int c = 0; c < 4; ++c) acc[r][c] = 0.0f;

    for (int kc = 0; kc < 168; kc += 32) {
        const int len = (168 - kc < 32) ? (168 - kc) : 32;   // 32,...,32,8
        // cooperative W chunk load: len*32 float4s
        for (int i = t; i < len * 32; i += 256) {
            const int krow = i >> 5;
            const int cc = (i & 31) * 4;
            const int kg = kc + krow;
            float4 v;
            if (kg < F_IN) v = *(const float4*)&Win[(size_t)kg * HID + cc];
            else           v = make_float4(0.f, 0.f, 0.f, 0.f);
            *(float4*)&Ws[krow * 128 + cc] = v;
        }
        __syncthreads();
        for (int k = 0; k < len; k += 2) {
            const float4 w0 = *(const float4*)&Ws[(k + 0) * 128 + c0];
            const float4 w1 = *(const float4*)&Ws[(k + 1) * 128 + c0];
#pragma unroll
            for (int r = 0; r < 4; ++r) {
                const float2 xv = *(const float2*)&xs[(r0 + r) * 168 + kc + k];
                acc[r][0] = fmaf(xv.x, w0.x, fmaf(xv.y, w1.x, acc[r][0]));
                acc[r][1] = fmaf(xv.x, w0.y, fmaf(xv.y, w1.y, acc[r][1]));
                acc[r][2] = fmaf(xv.x, w0.z, fmaf(xv.y, w1.z, acc[r][2]));
                acc[r][3] = fmaf(xv.x, w0.w, fmaf(xv.y, w1.w, acc[r][3]));
            }
        }
        __syncthreads();   // all waves done with this Ws chunk (and, last iter, with xs)
    }

    // ---- ReLU + bias; hs overwrites xs (safe: barrier above) ----
    const float4 bb = *(const float4*)&bin[c0];
#pragma unroll
    for (int r = 0; r < 4; ++r) {
        float4 h;
        h.x = fmaxf(acc[r][0] + bb.x, 0.0f);
        h.y = fmaxf(acc[r][1] + bb.y, 0.0f);
        h.z = fmaxf(acc[r][2] + bb.z, 0.0f);
        h.w = fmaxf(acc[r][3] + bb.w, 0.0f);
        *(float4*)&hs[(r0 + r) * 132 + c0] = h;
    }
    // hs visibility guaranteed by the first GEMM2 chunk's post-load barrier

    // ---- GEMM2: hW = h@Wgat, K=128, 4 chunks of 32 ----
#pragma unroll
    for (int r = 0; r < 4; ++r)
#pragma unroll
        for (int c = 0; c < 4; ++c) acc[r][c] = 0.0f;

    for (int kc = 0; kc < HID; kc += 32) {
        for (int i = t; i < 32 * 32; i += 256) {
            const int krow = i >> 5;
            const int cc = (i & 31) * 4;
            *(float4*)&Ws[krow * 128 + cc] =
                *(const float4*)&Wgat[(size_t)(kc + krow) * HID + cc];
        }
        __syncthreads();
        for (int k = 0; k < 32; k += 2) {
            const float4 w0 = *(const float4*)&Ws[(k + 0) * 128 + c0];
            const float4 w1 = *(const float4*)&Ws[(k + 1) * 128 + c0];
#pragma unroll
            for (int r = 0; r < 4; ++r) {
                const float2 hv = *(const float2*)&hs[(r0 + r) * 132 + kc + k];
                acc[r][0] = fmaf(hv.x, w0.x, fmaf(hv.y, w1.x, acc[r][0]));
                acc[r][1] = fmaf(hv.x, w0.y, fmaf(hv.y, w1.y, acc[r][1]));
                acc[r][2] = fmaf(hv.x, w0.z, fmaf(hv.y, w1.z, acc[r][2]));
                acc[r][3] = fmaf(hv.x, w0.w, fmaf(hv.y, w1.w, acc[r][3]));
            }
        }
        __syncthreads();
    }

    // ---- epilogue: store hW rows; per-head att dots ----
    const float4 atS = *(const float4*)&attS[c0];
    const float4 atD = *(const float4*)&attD[c0];
    const int head = cgrp >> 3;

    float ps[4], pd[4];
#pragma unroll
    for (int r = 0; r < 4; ++r) {
        float4 v;
        v.x = acc[r][0]; v.y = acc[r][1]; v.z = acc[r][2]; v.w = acc[r][3];
        *(float4*)&hW[(size_t)(row0 + r0 + r) * HID + c0] = v;
        ps[r] = v.x * atS.x + v.y * atS.y + v.z * atS.z + v.w * atS.w;
        pd[r] = v.x * atD.x + v.y * atD.y + v.z * atD.z + v.w * atD.w;
    }
#pragma unroll
    for (int off = 1; off <= 4; off <<= 1) {
#pragma unroll
        for (int r = 0; r < 4; ++r) {
            ps[r] += __shfl_xor(ps[r], off);
            pd[r] += __shfl_xor(pd[r], off);
        }
    }
    if ((cgrp & 7) == 0) {
#pragma unroll
        for (int r = 0; r < 4; ++r) {
            const int row = row0 + r0 + r;
            aS[row * 4 + head] = ps[r];
            aD[row * 4 + head] = pd[r];
        }
    }
}

// ---------------------------------------------------------------------------
// CSR build
// ---------------------------------------------------------------------------
__global__ __launch_bounds__(256) void k_hist(const int* __restrict__ ei,
                                              int* __restrict__ deg)
{
    int i = blockIdx.x * 256 + threadIdx.x;
    if (i >= TOT) return;
    int d = (i < E) ? ei[E + i] : (i - E);
    atomicAdd(&deg[d], 1);
}

__global__ __launch_bounds__(256) void k_scan1(const int* __restrict__ deg,
                                               int* __restrict__ bsum)
{
    __shared__ int sd[256];
    const int t = threadIdx.x, b = blockIdx.x;
    int s = 0;
    int i0 = b * SCAN_ELEMS + t * 4;
#pragma unroll
    for (int k = 0; k < 4; ++k) {
        int i = i0 + k;
        s += (i < N) ? deg[i] : 0;
    }
    sd[t] = s;
    __syncthreads();
    for (int off = 128; off >= 1; off >>= 1) {
        if (t < off) sd[t] += sd[t + off];
        __syncthreads();
    }
    if (t == 0) bsum[b] = sd[0];
}

__global__ void k_scan2(int* __restrict__ bsum, int* __restrict__ rowstart)
{
    if (threadIdx.x == 0) {
        int run = 0;
        for (int b = 0; b < SCAN_NB; ++b) {
            int v = bsum[b];
            bsum[b] = run;
            run += v;
        }
        rowstart[N] = run;  // == TOT
    }
}

__global__ __launch_bounds__(256) void k_scan3(const int* __restrict__ deg,
                                               const int* __restrict__ boff,
                                               int* __restrict__ rowstart,
                                               int* __restrict__ cursor)
{
    __shared__ int sd[256];
    const int t = threadIdx.x, b = blockIdx.x;
    const int i0 = b * SCAN_ELEMS + t * 4;
    int d0 = (i0 + 0 < N) ? deg[i0 + 0] : 0;
    int d1 = (i0 + 1 < N) ? deg[i0 + 1] : 0;
    int d2 = (i0 + 2 < N) ? deg[i0 + 2] : 0;
    int d3 = (i0 + 3 < N) ? deg[i0 + 3] : 0;
    int tsum = d0 + d1 + d2 + d3;
    sd[t] = tsum;
    __syncthreads();
    for (int off = 1; off < 256; off <<= 1) {
        int v = (t >= off) ? sd[t - off] : 0;
        __syncthreads();
        sd[t] += v;
        __syncthreads();
    }
    int base = boff[b] + sd[t] - tsum;
    int e0 = base, e1 = base + d0, e2 = e1 + d1, e3 = e2 + d2;
    if (i0 + 0 < N) { rowstart[i0 + 0] = e0; cursor[i0 + 0] = e0; }
    if (i0 + 1 < N) { rowstart[i0 + 1] = e1; cursor[i0 + 1] = e1; }
    if (i0 + 2 < N) { rowstart[i0 + 2] = e2; cursor[i0 + 2] = e2; }
    if (i0 + 3 < N) { rowstart[i0 + 3] = e3; cursor[i0 + 3] = e3; }
}

__global__ __launch_bounds__(256) void k_scatter(const int* __restrict__ ei,
                                                 int* __restrict__ cursor,
                                                 int* __restrict__ csr)
{
    int i = blockIdx.x * 256 + threadIdx.x;
    if (i >= TOT) return;
    int s, d;
    if (i < E) { s = ei[i]; d = ei[E + i]; } else { s = i - E; d = s; }
    int pos = atomicAdd(&cursor[d], 1);
    csr[pos] = s;
}

// ---------------------------------------------------------------------------
// K_agg: one wave per dst node; lane = slot(4) x colgroup(16); 4 edges in
// flight x unroll 2 = 8 outstanding hW-row gathers. No max pass (|e| < 1,
// exp cannot overflow; softmax is shift-invariant). No LDS -> full occupancy.
// ---------------------------------------------------------------------------
__global__ __launch_bounds__(256) void k_agg(
    const int* __restrict__ rowstart, const int* __restrict__ csr,
    const float* __restrict__ aS, const float* __restrict__ aD,
    const float4* __restrict__ hW4, const float4* __restrict__ bgat4,
    float4* __restrict__ gout4)
{
    const int t = threadIdx.x;
    const int n = blockIdx.x * 4 + (t >> 6);
    const int lane = t & 63;
    const int slot = lane >> 4;      // which of 4 parallel edges
    const int cg   = lane & 15;      // colgroup: cols [cg*8, cg*8+8)
    const int head = cg >> 2;

    const int r0 = rowstart[n], r1 = rowstart[n + 1];
    const float adh = aD[n * 4 + head];

    float4 acc0 = {0.f, 0.f, 0.f, 0.f};
    float4 acc1 = {0.f, 0.f, 0.f, 0.f};
    float ss = 0.0f;

    int j = r0 + slot;
    for (; j + 4 < r1; j += 8) {
        const int s0 = csr[j], s1 = csr[j + 4];
        const float x0 = __expf(lrelu(aS[s0 * 4 + head] + adh));
        const float x1 = __expf(lrelu(aS[s1 * 4 + head] + adh));
        const float4 ha0 = hW4[(size_t)s0 * 32 + cg * 2 + 0];
        const float4 hb0 = hW4[(size_t)s0 * 32 + cg * 2 + 1];
        const float4 ha1 = hW4[(size_t)s1 * 32 + cg * 2 + 0];
        const float4 hb1 = hW4[(size_t)s1 * 32 + cg * 2 + 1];
        acc0.x = fmaf(ha0.x, x0, acc0.x); acc0.y = fmaf(ha0.y, x0, acc0.y);
        acc0.z = fmaf(ha0.z, x0, acc0.z); acc0.w = fmaf(ha0.w, x0, acc0.w);
        acc1.x = fmaf(hb0.x, x0, acc1.x); acc1.y = fmaf(hb0.y, x0, acc1.y);
        acc1.z = fmaf(hb0.z, x0, acc1.z); acc1.w = fmaf(hb0.w, x0, acc1.w);
        acc0.x = fmaf(ha1.x, x1, acc0.x); acc0.y = fmaf(ha1.y, x1, acc0.y);
        acc0.z = fmaf(ha1.z, x1, acc0.z); acc0.w = fmaf(ha1.w, x1, acc0.w);
        acc1.x = fmaf(hb1.x, x1, acc1.x); acc1.y = fmaf(hb1.y, x1, acc1.y);
        acc1.z = fmaf(hb1.z, x1, acc1.z); acc1.w = fmaf(hb1.w, x1, acc1.w);
        ss += x0 + x1;
    }
    if (j < r1) {
        const int s0 = csr[j];
        const float x0 = __expf(lrelu(aS[s0 * 4 + head] + adh));
        const float4 ha0 = hW4[(size_t)s0 * 32 + cg * 2 + 0];
        const float4 hb0 = hW4[(size_t)s0 * 32 + cg * 2 + 1];
        acc0.x = fmaf(ha0.x, x0, acc0.x); acc0.y = fmaf(ha0.y, x0, acc0.y);
        acc0.z = fmaf(ha0.z, x0, acc0.z); acc0.w = fmaf(ha0.w, x0, acc0.w);
        acc1.x = fmaf(hb0.x, x0, acc1.x); acc1.y = fmaf(hb0.y, x0, acc1.y);
        acc1.z = fmaf(hb0.z, x0, acc1.z); acc1.w = fmaf(hb0.w, x0, acc1.w);
        ss += x0;
    }

#pragma unroll
    for (int off = 16; off <= 32; off <<= 1) {
        acc0.x += __shfl_xor(acc0.x, off); acc0.y += __shfl_xor(acc0.y, off);
        acc0.z += __shfl_xor(acc0.z, off); acc0.w += __shfl_xor(acc0.w, off);
        acc1.x += __shfl_xor(acc1.x, off); acc1.y += __shfl_xor(acc1.y, off);
        acc1.z += __shfl_xor(acc1.z, off); acc1.w += __shfl_xor(acc1.w, off);
        ss += __shfl_xor(ss, off);
    }

    if (slot == 0) {
        const float inv = 1.0f / (ss + 1e-16f);
        const float4 bg0 = bgat4[cg * 2 + 0];
        const float4 bg1 = bgat4[cg * 2 + 1];
        float4 o0, o1;
        o0.x = acc0.x * inv + bg0.x; o0.y = acc0.y * inv + bg0.y;
        o0.z = acc0.z * inv + bg0.z; o0.w = acc0.w * inv + bg0.w;
        o1.x = acc1.x * inv + bg1.x; o1.y = acc1.y * inv + bg1.y;
        o1.z = acc1.z * inv + bg1.z; o1.w = acc1.w * inv + bg1.w;
        gout4[(size_t)n * 32 + cg * 2 + 0] = o0;
        gout4[(size_t)n * 32 + cg * 2 + 1] = o1;
    }
}

// ---------------------------------------------------------------------------
// K_mlp: h2 = relu(gout@W1+b1); logits = h2@W2+b2. One wave per node,
// 16 nodes/block (4 waves x 4 iters), W1 staged in LDS.
// ---------------------------------------------------------------------------
__global__ __launch_bounds__(256) void k_mlp(
    const float* __restrict__ gout,
    const float* __restrict__ W1, const float* __restrict__ b1,
    const float* __restrict__ W2, const float* __restrict__ b2,
    float2* __restrict__ out)
{
    __shared__ __align__(16) float W1l[HID * 64];
    __shared__ __align__(16) float rowbuf[4][HID];
    __shared__ float b1l[64];
    __shared__ float W2l[128];
    __shared__ float b2l[2];

    const int t = threadIdx.x;
    for (int idx = t; idx < HID * 64; idx += 256) W1l[idx] = W1[idx];
    if (t < 64) b1l[t] = b1[t];
    if (t < 128) W2l[t] = W2[t];
    if (t < 2) b2l[t] = b2[t];
    __syncthreads();

    const int w = t >> 6, lane = t & 63;

    for (int it = 0; it < 4; ++it) {
        const int n = blockIdx.x * 16 + w * 4 + it;
        const float2 oa = *(const float2*)&gout[(size_t)n * HID + lane * 2];
        rowbuf[w][lane * 2 + 0] = oa.x;
        rowbuf[w][lane * 2 + 1] = oa.y;

        float acc = b1l[lane];
#pragma unroll 4
        for (int k = 0; k < HID; k += 4) {
            const float4 bv = *(const float4*)&rowbuf[w][k];
            acc = fmaf(bv.x, W1l[(k + 0) * 64 + lane], acc);
            acc = fmaf(bv.y, W1l[(k + 1) * 64 + lane], acc);
            acc = fmaf(bv.z, W1l[(k + 2) * 64 + lane], acc);
            acc = fmaf(bv.w, W1l[(k + 3) * 64 + lane], acc);
        }
        acc = acc > 0.0f ? acc : 0.0f;

        float l0 = acc * W2l[lane * 2 + 0];
        float l1 = acc * W2l[lane * 2 + 1];
#pragma unroll
        for (int off = 32; off >= 1; off >>= 1) {
            l0 += __shfl_xor(l0, off);
            l1 += __shfl_xor(l1, off);
        }
        if (lane == 0) out[n] = make_float2(l0 + b2l[0], l1 + b2l[1]);
    }
}

extern "C" void kernel_launch(void* const* d_in, const int* in_sizes, int n_in,
                              void* d_out, int out_size, void* d_ws, size_t ws_size,
                              hipStream_t stream) {
    const float* x     = (const float*)d_in[0];
    const int*   ei    = (const int*)d_in[1];
    const float* Win   = (const float*)d_in[2];
    const float* bin   = (const float*)d_in[3];
    const float* Wgat  = (const float*)d_in[4];
    const float* attS  = (const float*)d_in[5];
    const float* attD  = (const float*)d_in[6];
    const float* bgat  = (const float*)d_in[7];
    const float* W1    = (const float*)d_in[8];
    const float* b1    = (const float*)d_in[9];
    const float* W2    = (const float*)d_in[10];
    const float* b2    = (const float*)d_in[11];

    char* ws = (char*)d_ws;
    float* hW    = (float*)(ws + HW_OFF);
    float* aS    = (float*)(ws + ASRC_OFF);
    float* aD    = (float*)(ws + ADST_OFF);
    int*   deg   = (int*)(ws + DEG_OFF);
    int*   row   = (int*)(ws + ROW_OFF);
    int*   cur   = (int*)(ws + CUR_OFF);
    int*   bsum  = (int*)(ws + BSUM_OFF);
    int*   csr   = (int*)(ws + CSR_OFF);
    float* gout  = (float*)(ws + GOUT_OFF);

    hipMemsetAsync(ws + DEG_OFF, 0, N * sizeof(int), stream);

    k_proj<<<N / 32, 256, 0, stream>>>(x, Win, bin, Wgat, attS, attD, hW, aS, aD);
    k_hist<<<(TOT + 255) / 256, 256, 0, stream>>>(ei, deg);
    k_scan1<<<SCAN_NB, 256, 0, stream>>>(deg, bsum);
    k_scan2<<<1, 64, 0, stream>>>(bsum, row);
    k_scan3<<<SCAN_NB, 256, 0, stream>>>(deg, bsum, row, cur);
    k_scatter<<<(TOT + 255) / 256, 256, 0, stream>>>(ei, cur, csr);
    k_agg<<<N / 4, 256, 0, stream>>>(row, csr, aS, aD, (const float4*)hW,
                                     (const float4*)bgat, (float4*)gout);
    k_mlp<<<N / 16, 256, 0, stream>>>(gout, W1, b1, W2, b2, (float2*)d_out);
}

// Round 6
// 618.207 us; speedup vs baseline: 1.0914x; 1.0914x over previous
//
#include <hip/hip_runtime.h>

#define DEVFN __device__ __forceinline__

constexpr int N    = 100000;
constexpr int F_IN = 166;
constexpr int HID  = 128;
constexpr int E    = 1600000;
constexpr int TOT  = E + N;          // edges + self-loops

// ---- workspace layout (bytes, all 16B-aligned) ----
constexpr size_t HW_OFF   = 0;            // hW [N,128] f32      51.2 MB
constexpr size_t ASRC_OFF = 51200000;     // a_src [N,4] f32      1.6 MB
constexpr size_t ADST_OFF = 52800000;     // a_dst [N,4] f32      1.6 MB
constexpr size_t DEG_OFF  = 54400000;     // deg [N] i32        400 KB (zeroed)
constexpr size_t ROW_OFF  = 54800000;     // rowstart [N+1] i32
constexpr size_t CUR_OFF  = 55300000;     // cursor [N] i32
constexpr size_t BSUM_OFF = 55700000;     // block sums [128] i32
constexpr size_t CSR_OFF  = 55710000;     // csr_src [TOT] i32   27.2 MB
constexpr size_t GOUT_OFF = 82910016;     // gat out [N,128] f32 51.2 MB

constexpr int SCAN_ELEMS = 1024;
constexpr int SCAN_NB    = (N + SCAN_ELEMS - 1) / SCAN_ELEMS;  // 98

constexpr int PROJ_ROWS  = 64;
constexpr int PROJ_NB    = (N + PROJ_ROWS - 1) / PROJ_ROWS;    // 1563

DEVFN float lrelu(float e) { return e > 0.0f ? e : 0.2f * e; }

// ---------------------------------------------------------------------------
// K1: h = relu(x@W_in+b_in), hW = h@W_gat, a_src/a_dst = per-head hW·att
// Tile 64 rows x 128 cols, 256 threads, 8 rows x 4 cols per thread.
// W from global (VMEM/L1 pipe), x from LDS (broadcast ds_read_b128, 2-way
// aliasing = free). Per 4-k step: 4 vmem + 8 lds + 128 FMA (~91% FMA issue).
// R5 lesson: staging W in LDS puts W on the same pipe as x and adds barrier
// drains -> regression. hs reuses the xs buffer (stride 132).
// Tail of the kernel: grid-stride dst-degree histogram (fused k_hist).
// ---------------------------------------------------------------------------
__global__ __launch_bounds__(256) void k_proj(
    const float* __restrict__ x, const float* __restrict__ Win,
    const float* __restrict__ bin, const float* __restrict__ Wgat,
    const float* __restrict__ attS, const float* __restrict__ attD,
    float* __restrict__ hW, float* __restrict__ aS, float* __restrict__ aD,
    const int* __restrict__ ei, int* __restrict__ deg)
{
    __shared__ __align__(16) float xs[PROJ_ROWS * 168];   // 43 KB; hs reuses (stride 132)
    float* hs = xs;

    const int t = threadIdx.x;
    const int row0 = blockIdx.x * PROJ_ROWS;
    const int cgrp = t & 31, rgrp = t >> 5;
    const int c0 = cgrp * 4;          // 4 cols
    const int r0 = rgrp * 8;          // 8 rows

    // ---- stage x tile (row-major, stride 168), float2 granules ----
    for (int idx = t; idx < PROJ_ROWS * 83; idx += 256) {
        const int r = idx / 83, kk = idx - r * 83;
        float2 v = make_float2(0.f, 0.f);
        if (row0 + r < N)
            v = *(const float2*)&x[(size_t)(row0 + r) * F_IN + 2 * kk];
        *(float2*)&xs[r * 168 + 2 * kk] = v;
    }
    __syncthreads();

    // ---- GEMM1: h = relu(x@Win + bin) ----
    float acc[8][4];
#pragma unroll
    for (int r = 0; r < 8; ++r)
#pragma unroll
        for (int c = 0; c < 4; ++c) acc[r][c] = 0.0f;

#pragma unroll 2
    for (int k = 0; k < 164; k += 4) {
        const float4 w0 = *(const float4*)&Win[(size_t)(k + 0) * HID + c0];
        const float4 w1 = *(const float4*)&Win[(size_t)(k + 1) * HID + c0];
        const float4 w2 = *(const float4*)&Win[(size_t)(k + 2) * HID + c0];
        const float4 w3 = *(const float4*)&Win[(size_t)(k + 3) * HID + c0];
#pragma unroll
        for (int r = 0; r < 8; ++r) {
            const float4 xv = *(const float4*)&xs[(r0 + r) * 168 + k];
            acc[r][0] = fmaf(xv.x, w0.x, fmaf(xv.y, w1.x,
                        fmaf(xv.z, w2.x, fmaf(xv.w, w3.x, acc[r][0]))));
            acc[r][1] = fmaf(xv.x, w0.y, fmaf(xv.y, w1.y,
                        fmaf(xv.z, w2.y, fmaf(xv.w, w3.y, acc[r][1]))));
            acc[r][2] = fmaf(xv.x, w0.z, fmaf(xv.y, w1.z,
                        fmaf(xv.z, w2.z, fmaf(xv.w, w3.z, acc[r][2]))));
            acc[r][3] = fmaf(xv.x, w0.w, fmaf(xv.y, w1.w,
                        fmaf(xv.z, w2.w, fmaf(xv.w, w3.w, acc[r][3]))));
        }
    }
    {   // k = 164,165 tail (F_IN = 166)
        const float4 w0 = *(const float4*)&Win[(size_t)164 * HID + c0];
        const float4 w1 = *(const float4*)&Win[(size_t)165 * HID + c0];
#pragma unroll
        for (int r = 0; r < 8; ++r) {
            const float2 xv = *(const float2*)&xs[(r0 + r) * 168 + 164];
            acc[r][0] = fmaf(xv.x, w0.x, fmaf(xv.y, w1.x, acc[r][0]));
            acc[r][1] = fmaf(xv.x, w0.y, fmaf(xv.y, w1.y, acc[r][1]));
            acc[r][2] = fmaf(xv.x, w0.z, fmaf(xv.y, w1.z, acc[r][2]));
            acc[r][3] = fmaf(xv.x, w0.w, fmaf(xv.y, w1.w, acc[r][3]));
        }
    }

    const float4 bb = *(const float4*)&bin[c0];
    __syncthreads();   // all waves done reading xs; safe to overwrite with hs

#pragma unroll
    for (int r = 0; r < 8; ++r) {
        float4 h;
        h.x = fmaxf(acc[r][0] + bb.x, 0.0f);
        h.y = fmaxf(acc[r][1] + bb.y, 0.0f);
        h.z = fmaxf(acc[r][2] + bb.z, 0.0f);
        h.w = fmaxf(acc[r][3] + bb.w, 0.0f);
        *(float4*)&hs[(r0 + r) * 132 + c0] = h;
    }
    __syncthreads();

    // ---- GEMM2: hW = h@Wgat (K = 128) ----
#pragma unroll
    for (int r = 0; r < 8; ++r)
#pragma unroll
        for (int c = 0; c < 4; ++c) acc[r][c] = 0.0f;

#pragma unroll 2
    for (int k = 0; k < HID; k += 4) {
        const float4 w0 = *(const float4*)&Wgat[(size_t)(k + 0) * HID + c0];
        const float4 w1 = *(const float4*)&Wgat[(size_t)(k + 1) * HID + c0];
        const float4 w2 = *(const float4*)&Wgat[(size_t)(k + 2) * HID + c0];
        const float4 w3 = *(const float4*)&Wgat[(size_t)(k + 3) * HID + c0];
#pragma unroll
        for (int r = 0; r < 8; ++r) {
            const float4 hv = *(const float4*)&hs[(r0 + r) * 132 + k];
            acc[r][0] = fmaf(hv.x, w0.x, fmaf(hv.y, w1.x,
                        fmaf(hv.z, w2.x, fmaf(hv.w, w3.x, acc[r][0]))));
            acc[r][1] = fmaf(hv.x, w0.y, fmaf(hv.y, w1.y,
                        fmaf(hv.z, w2.y, fmaf(hv.w, w3.y, acc[r][1]))));
            acc[r][2] = fmaf(hv.x, w0.z, fmaf(hv.y, w1.z,
                        fmaf(hv.z, w2.z, fmaf(hv.w, w3.z, acc[r][2]))));
            acc[r][3] = fmaf(hv.x, w0.w, fmaf(hv.y, w1.w,
                        fmaf(hv.z, w2.w, fmaf(hv.w, w3.w, acc[r][3]))));
        }
    }

    // ---- epilogue: store hW rows; per-head att dots ----
    const float4 atS = *(const float4*)&attS[c0];
    const float4 atD = *(const float4*)&attD[c0];
    const int head = cgrp >> 3;

#pragma unroll
    for (int r = 0; r < 8; ++r) {
        const int row = row0 + r0 + r;
        float4 v;
        v.x = acc[r][0]; v.y = acc[r][1]; v.z = acc[r][2]; v.w = acc[r][3];
        if (row < N)
            *(float4*)&hW[(size_t)row * HID + c0] = v;
        float ps = v.x * atS.x + v.y * atS.y + v.z * atS.z + v.w * atS.w;
        float pd = v.x * atD.x + v.y * atD.y + v.z * atD.z + v.w * atD.w;
#pragma unroll
        for (int off = 1; off <= 4; off <<= 1) {
            ps += __shfl_xor(ps, off);
            pd += __shfl_xor(pd, off);
        }
        if ((cgrp & 7) == 0 && row < N) {
            aS[row * 4 + head] = ps;
            aD[row * 4 + head] = pd;
        }
    }

    // ---- fused dst-degree histogram (k_hist) ----
    const int stride = gridDim.x * 256;
    for (int i = blockIdx.x * 256 + t; i < TOT; i += stride) {
        const int d = (i < E) ? ei[E + i] : (i - E);
        atomicAdd(&deg[d], 1);
    }
}

// ---------------------------------------------------------------------------
// CSR build (scan + scatter)
// ---------------------------------------------------------------------------
__global__ __launch_bounds__(256) void k_scan1(const int* __restrict__ deg,
                                               int* __restrict__ bsum)
{
    __shared__ int sd[256];
    const int t = threadIdx.x, b = blockIdx.x;
    int s = 0;
    int i0 = b * SCAN_ELEMS + t * 4;
#pragma unroll
    for (int k = 0; k < 4; ++k) {
        int i = i0 + k;
        s += (i < N) ? deg[i] : 0;
    }
    sd[t] = s;
    __syncthreads();
    for (int off = 128; off >= 1; off >>= 1) {
        if (t < off) sd[t] += sd[t + off];
        __syncthreads();
    }
    if (t == 0) bsum[b] = sd[0];
}

__global__ void k_scan2(int* __restrict__ bsum, int* __restrict__ rowstart)
{
    if (threadIdx.x == 0) {
        int run = 0;
        for (int b = 0; b < SCAN_NB; ++b) {
            int v = bsum[b];
            bsum[b] = run;
            run += v;
        }
        rowstart[N] = run;  // == TOT
    }
}

__global__ __launch_bounds__(256) void k_scan3(const int* __restrict__ deg,
                                               const int* __restrict__ boff,
                                               int* __restrict__ rowstart,
                                               int* __restrict__ cursor)
{
    __shared__ int sd[256];
    const int t = threadIdx.x, b = blockIdx.x;
    const int i0 = b * SCAN_ELEMS + t * 4;
    int d0 = (i0 + 0 < N) ? deg[i0 + 0] : 0;
    int d1 = (i0 + 1 < N) ? deg[i0 + 1] : 0;
    int d2 = (i0 + 2 < N) ? deg[i0 + 2] : 0;
    int d3 = (i0 + 3 < N) ? deg[i0 + 3] : 0;
    int tsum = d0 + d1 + d2 + d3;
    sd[t] = tsum;
    __syncthreads();
    for (int off = 1; off < 256; off <<= 1) {
        int v = (t >= off) ? sd[t - off] : 0;
        __syncthreads();
        sd[t] += v;
        __syncthreads();
    }
    int base = boff[b] + sd[t] - tsum;
    int e0 = base, e1 = base + d0, e2 = e1 + d1, e3 = e2 + d2;
    if (i0 + 0 < N) { rowstart[i0 + 0] = e0; cursor[i0 + 0] = e0; }
    if (i0 + 1 < N) { rowstart[i0 + 1] = e1; cursor[i0 + 1] = e1; }
    if (i0 + 2 < N) { rowstart[i0 + 2] = e2; cursor[i0 + 2] = e2; }
    if (i0 + 3 < N) { rowstart[i0 + 3] = e3; cursor[i0 + 3] = e3; }
}

__global__ __launch_bounds__(256) void k_scatter(const int* __restrict__ ei,
                                                 int* __restrict__ cursor,
                                                 int* __restrict__ csr)
{
    int i = blockIdx.x * 256 + threadIdx.x;
    if (i >= TOT) return;
    int s, d;
    if (i < E) { s = ei[i]; d = ei[E + i]; } else { s = i - E; d = s; }
    int pos = atomicAdd(&cursor[d], 1);
    csr[pos] = s;
}

// ---------------------------------------------------------------------------
// K_agg: one wave per dst node; lane = slot(4) x colgroup(16); 4 edges in
// flight x unroll 2 = 8 outstanding hW-row gathers. No max pass (|e| < 1,
// exp cannot overflow; softmax is shift-invariant). No LDS -> full occupancy.
// ---------------------------------------------------------------------------
__global__ __launch_bounds__(256) void k_agg(
    const int* __restrict__ rowstart, const int* __restrict__ csr,
    const float* __restrict__ aS, const float* __restrict__ aD,
    const float4* __restrict__ hW4, const float4* __restrict__ bgat4,
    float4* __restrict__ gout4)
{
    const int t = threadIdx.x;
    const int n = blockIdx.x * 4 + (t >> 6);
    const int lane = t & 63;
    const int slot = lane >> 4;      // which of 4 parallel edges
    const int cg   = lane & 15;      // colgroup: cols [cg*8, cg*8+8)
    const int head = cg >> 2;

    const int r0 = rowstart[n], r1 = rowstart[n + 1];
    const float adh = aD[n * 4 + head];

    float4 acc0 = {0.f, 0.f, 0.f, 0.f};
    float4 acc1 = {0.f, 0.f, 0.f, 0.f};
    float ss = 0.0f;

    int j = r0 + slot;
    for (; j + 4 < r1; j += 8) {
        const int s0 = csr[j], s1 = csr[j + 4];
        const float x0 = __expf(lrelu(aS[s0 * 4 + head] + adh));
        const float x1 = __expf(lrelu(aS[s1 * 4 + head] + adh));
        const float4 ha0 = hW4[(size_t)s0 * 32 + cg * 2 + 0];
        const float4 hb0 = hW4[(size_t)s0 * 32 + cg * 2 + 1];
        const float4 ha1 = hW4[(size_t)s1 * 32 + cg * 2 + 0];
        const float4 hb1 = hW4[(size_t)s1 * 32 + cg * 2 + 1];
        acc0.x = fmaf(ha0.x, x0, acc0.x); acc0.y = fmaf(ha0.y, x0, acc0.y);
        acc0.z = fmaf(ha0.z, x0, acc0.z); acc0.w = fmaf(ha0.w, x0, acc0.w);
        acc1.x = fmaf(hb0.x, x0, acc1.x); acc1.y = fmaf(hb0.y, x0, acc1.y);
        acc1.z = fmaf(hb0.z, x0, acc1.z); acc1.w = fmaf(hb0.w, x0, acc1.w);
        acc0.x = fmaf(ha1.x, x1, acc0.x); acc0.y = fmaf(ha1.y, x1, acc0.y);
        acc0.z = fmaf(ha1.z, x1, acc0.z); acc0.w = fmaf(ha1.w, x1, acc0.w);
        acc1.x = fmaf(hb1.x, x1, acc1.x); acc1.y = fmaf(hb1.y, x1, acc1.y);
        acc1.z = fmaf(hb1.z, x1, acc1.z); acc1.w = fmaf(hb1.w, x1, acc1.w);
        ss += x0 + x1;
    }
    if (j < r1) {
        const int s0 = csr[j];
        const float x0 = __expf(lrelu(aS[s0 * 4 + head] + adh));
        const float4 ha0 = hW4[(size_t)s0 * 32 + cg * 2 + 0];
        const float4 hb0 = hW4[(size_t)s0 * 32 + cg * 2 + 1];
        acc0.x = fmaf(ha0.x, x0, acc0.x); acc0.y = fmaf(ha0.y, x0, acc0.y);
        acc0.z = fmaf(ha0.z, x0, acc0.z); acc0.w = fmaf(ha0.w, x0, acc0.w);
        acc1.x = fmaf(hb0.x, x0, acc1.x); acc1.y = fmaf(hb0.y, x0, acc1.y);
        acc1.z = fmaf(hb0.z, x0, acc1.z); acc1.w = fmaf(hb0.w, x0, acc1.w);
        ss += x0;
    }

#pragma unroll
    for (int off = 16; off <= 32; off <<= 1) {
        acc0.x += __shfl_xor(acc0.x, off); acc0.y += __shfl_xor(acc0.y, off);
        acc0.z += __shfl_xor(acc0.z, off); acc0.w += __shfl_xor(acc0.w, off);
        acc1.x += __shfl_xor(acc1.x, off); acc1.y += __shfl_xor(acc1.y, off);
        acc1.z += __shfl_xor(acc1.z, off); acc1.w += __shfl_xor(acc1.w, off);
        ss += __shfl_xor(ss, off);
    }

    if (slot == 0) {
        const float inv = 1.0f / (ss + 1e-16f);
        const float4 bg0 = bgat4[cg * 2 + 0];
        const float4 bg1 = bgat4[cg * 2 + 1];
        float4 o0, o1;
        o0.x = acc0.x * inv + bg0.x; o0.y = acc0.y * inv + bg0.y;
        o0.z = acc0.z * inv + bg0.z; o0.w = acc0.w * inv + bg0.w;
        o1.x = acc1.x * inv + bg1.x; o1.y = acc1.y * inv + bg1.y;
        o1.z = acc1.z * inv + bg1.z; o1.w = acc1.w * inv + bg1.w;
        gout4[(size_t)n * 32 + cg * 2 + 0] = o0;
        gout4[(size_t)n * 32 + cg * 2 + 1] = o1;
    }
}

// ---------------------------------------------------------------------------
// K_mlp: h2 = relu(gout@W1+b1); logits = h2@W2+b2. One wave per node,
// 16 nodes/block (4 waves x 4 iters), W1 staged in LDS.
// ---------------------------------------------------------------------------
__global__ __launch_bounds__(256) void k_mlp(
    const float* __restrict__ gout,
    const float* __restrict__ W1, const float* __restrict__ b1,
    const float* __restrict__ W2, const float* __restrict__ b2,
    float2* __restrict__ out)
{
    __shared__ __align__(16) float W1l[HID * 64];
    __shared__ __align__(16) float rowbuf[4][HID];
    __shared__ float b1l[64];
    __shared__ float W2l[128];
    __shared__ float b2l[2];

    const int t = threadIdx.x;
    for (int idx = t; idx < HID * 64; idx += 256) W1l[idx] = W1[idx];
    if (t < 64) b1l[t] = b1[t];
    if (t < 128) W2l[t] = W2[t];
    if (t < 2) b2l[t] = b2[t];
    __syncthreads();

    const int w = t >> 6, lane = t & 63;

    for (int it = 0; it < 4; ++it) {
        const int n = blockIdx.x * 16 + w * 4 + it;
        const float2 oa = *(const float2*)&gout[(size_t)n * HID + lane * 2];
        rowbuf[w][lane * 2 + 0] = oa.x;
        rowbuf[w][lane * 2 + 1] = oa.y;

        float acc = b1l[lane];
#pragma unroll 4
        for (int k = 0; k < HID; k += 4) {
            const float4 bv = *(const float4*)&rowbuf[w][k];
            acc = fmaf(bv.x, W1l[(k + 0) * 64 + lane], acc);
            acc = fmaf(bv.y, W1l[(k + 1) * 64 + lane], acc);
            acc = fmaf(bv.z, W1l[(k + 2) * 64 + lane], acc);
            acc = fmaf(bv.w, W1l[(k + 3) * 64 + lane], acc);
        }
        acc = acc > 0.0f ? acc : 0.0f;

        float l0 = acc * W2l[lane * 2 + 0];
        float l1 = acc * W2l[lane * 2 + 1];
#pragma unroll
        for (int off = 32; off >= 1; off >>= 1) {
            l0 += __shfl_xor(l0, off);
            l1 += __shfl_xor(l1, off);
        }
        if (lane == 0) out[n] = make_float2(l0 + b2l[0], l1 + b2l[1]);
    }
}

extern "C" void kernel_launch(void* const* d_in, const int* in_sizes, int n_in,
                              void* d_out, int out_size, void* d_ws, size_t ws_size,
                              hipStream_t stream) {
    const float* x     = (const float*)d_in[0];
    const int*   ei    = (const int*)d_in[1];
    const float* Win   = (const float*)d_in[2];
    const float* bin   = (const float*)d_in[3];
    const float* Wgat  = (const float*)d_in[4];
    const float* attS  = (const float*)d_in[5];
    const float* attD  = (const float*)d_in[6];
    const float* bgat  = (const float*)d_in[7];
    const float* W1    = (const float*)d_in[8];
    const float* b1    = (const float*)d_in[9];
    const float* W2    = (const float*)d_in[10];
    const float* b2    = (const float*)d_in[11];

    char* ws = (char*)d_ws;
    float* hW    = (float*)(ws + HW_OFF);
    float* aS    = (float*)(ws + ASRC_OFF);
    float* aD    = (float*)(ws + ADST_OFF);
    int*   deg   = (int*)(ws + DEG_OFF);
    int*   row   = (int*)(ws + ROW_OFF);
    int*   cur   = (int*)(ws + CUR_OFF);
    int*   bsum  = (int*)(ws + BSUM_OFF);
    int*   csr   = (int*)(ws + CSR_OFF);
    float* gout  = (float*)(ws + GOUT_OFF);

    hipMemsetAsync(ws + DEG_OFF, 0, N * sizeof(int), stream);

    k_proj<<<PROJ_NB, 256, 0, stream>>>(x, Win, bin, Wgat, attS, attD,
                                        hW, aS, aD, ei, deg);
    k_scan1<<<SCAN_NB, 256, 0, stream>>>(deg, bsum);
    k_scan2<<<1, 64, 0, stream>>>(bsum, row);
    k_scan3<<<SCAN_NB, 256, 0, stream>>>(deg, bsum, row, cur);
    k_scatter<<<(TOT + 255) / 256, 256, 0, stream>>>(ei, cur, csr);
    k_agg<<<N / 4, 256, 0, stream>>>(row, csr, aS, aD, (const float4*)hW,
                                     (const float4*)bgat, (float4*)gout);
    k_mlp<<<N / 16, 256, 0, stream>>>(gout, W1, b1, W2, b2, (float2*)d_out);
}